// Round 12
// baseline (150.298 us; speedup 1.0000x reference)
//
#include <hip/hip_runtime.h>

// GIN block, 2 layers: h = mlp(h + segsum(h[src], dst)); out = (h*mask, x)
// N=100000, E=1600000, D=64.
// Round-12 (from verified round-11):
//  - agg: FOUR nodes per wave (quad accumulators, 4 idx + 16 gathers in flight) --
//    attacks the latency-bound gather with 2x more MLP than round-11's 2-node.
//  - ovf_fix folded into agg (uniform ovfCnt check, f32 patch before bf16 pack):
//    10 -> 8 dispatches, CAS path gone.
//  - setup/scatter/bucketize/cvtx/mlp_mfma unchanged (verified rounds 7-11).

#define NN 100000
#define EE 1600000
#define CAP 48
#define NBIN 1024
#define BINCAP 2688
#define CHB 6250
#define OVF_CAPN 8000

// ws layout (ints):
//   gcur     @ 0        (1024)   -- init b*BINCAP by setup_k
//   ovfCnt   @ 1024     (1)      -- zeroed by setup_k
//   ovf      @ 1026     (2*8000)
//   cnt      @ 19200    (100000)
//   bucket   @ 119296   (NN*CAP)
//   binned   @ 4919296  (NBIN*BINCAP = 2752512) } binned dead after bucketize ->
//   hb/hb1   @ 4919296  (3200032)               } bf16 h / h1 + zero row at hb[NN]
//   pw       @ 8119328  (16384 shorts)
#define OVFC_OFF   1024
#define OVF_OFF    1026
#define CNT_OFF    19200
#define BUCK_OFF   119296
#define BINNED_OFF 4919296
#define HB_OFF     4919296
#define PW_OFF     8119328

typedef __attribute__((ext_vector_type(8))) short s8v;
typedef __attribute__((ext_vector_type(4))) float f4v;

union U8 { unsigned u[4]; s8v s; };

static __device__ __forceinline__ unsigned short f2bf(float f) {
  unsigned u = __float_as_uint(f);
  return (unsigned short)((u + 0x7FFF + ((u >> 16) & 1)) >> 16);  // RTNE
}
static __device__ __forceinline__ float bf2f(unsigned short s) {
  return __uint_as_float(((unsigned)s) << 16);
}
static __device__ __forceinline__ unsigned pk2(float lo, float hi) {
  return (unsigned)f2bf(lo) | ((unsigned)f2bf(hi) << 16);
}

// setup: gcur[b] = b*BINCAP, ovfCnt = 0, pack W[64][64] f32 row-major -> A-frag bf16:
// pw[m*4096 + ((t*2+ks)*64 + l)*8 + j] = bf16(W[ks*32 + (l>>4)*8 + j][t*16 + (l&15)])
__global__ __launch_bounds__(256) void setup_k(const float* __restrict__ W1a,
                                               const float* __restrict__ W2a,
                                               const float* __restrict__ W1b,
                                               const float* __restrict__ W2b,
                                               unsigned short* __restrict__ pw,
                                               int* __restrict__ wsp) {
  const int t = threadIdx.x;
#pragma unroll
  for (int i = t; i < NBIN; i += 256) wsp[i] = i * BINCAP;  // gcur
  if (t == 0) wsp[OVFC_OFF] = 0;
  const float* Ws[4] = {W1a, W2a, W1b, W2b};
#pragma unroll
  for (int m = 0; m < 4; ++m) {
    const float* __restrict__ W = Ws[m];
#pragma unroll 1
    for (int i = 0; i < 16; ++i) {
      const int e = i * 256 + t;           // 0..4095
      const int j = e & 7;
      const int lv = (e >> 3) & 63;
      const int ks = (e >> 9) & 1;
      const int tt = e >> 10;
      const int k = ks * 32 + (lv >> 4) * 8 + j;
      const int n = tt * 16 + (lv & 15);
      pw[m * 4096 + e] = f2bf(W[k * 64 + n]);
    }
  }
}

// single-pass binning: LDS block-hist -> one global cursor bump per (block,bin) -> scatter
__global__ __launch_bounds__(256) void scatter_k(const int* __restrict__ src,
                                                 const int* __restrict__ dst,
                                                 int* __restrict__ gcur,
                                                 int* __restrict__ binned,
                                                 int* __restrict__ ovf) {
  __shared__ int hist[NBIN], base[NBIN], lcnt[NBIN];
  const int t = threadIdx.x;
#pragma unroll
  for (int b = t; b < NBIN; b += 256) { hist[b] = 0; lcnt[b] = 0; }
  __syncthreads();
  const int s = blockIdx.x * CHB;
#pragma unroll 1
  for (int p = t; p < CHB / 2; p += 256) {
    const int2 dd = *reinterpret_cast<const int2*>(dst + s + 2 * p);
    atomicAdd(&hist[dd.x >> 7], 1);
    atomicAdd(&hist[dd.y >> 7], 1);
  }
  __syncthreads();
#pragma unroll
  for (int b = t; b < NBIN; b += 256) {
    const int c = hist[b];
    base[b] = c ? atomicAdd(&gcur[b], c) : 0;
  }
  __syncthreads();
#pragma unroll 1
  for (int p = t; p < CHB / 2; p += 256) {
    const int i = s + 2 * p;
    const int2 dd = *reinterpret_cast<const int2*>(dst + i);
    const int2 ss = *reinterpret_cast<const int2*>(src + i);
    {
      const int bin = dd.x >> 7;
      const int slot = base[bin] + atomicAdd(&lcnt[bin], 1);
      if (slot < (bin + 1) * BINCAP) {
        binned[slot] = ((dd.x & 127) << 17) | ss.x;
      } else {
        const int q = atomicAdd(&ovf[-2], 1);
        if (q < OVF_CAPN) { ovf[2 * q] = dd.x; ovf[2 * q + 1] = ss.x; }
      }
    }
    {
      const int bin = dd.y >> 7;
      const int slot = base[bin] + atomicAdd(&lcnt[bin], 1);
      if (slot < (bin + 1) * BINCAP) {
        binned[slot] = ((dd.y & 127) << 17) | ss.y;
      } else {
        const int q = atomicAdd(&ovf[-2], 1);
        if (q < OVF_CAPN) { ovf[2 * q] = dd.y; ovf[2 * q + 1] = ss.y; }
      }
    }
  }
}

__global__ __launch_bounds__(256) void bucketize_k(const int* __restrict__ gcur,
                                                   const int* __restrict__ binned,
                                                   int* __restrict__ bucket,
                                                   int* __restrict__ cnt,
                                                   int* __restrict__ ovf) {
  __shared__ int c128[128];
  const int t = threadIdx.x;
  const int bin = blockIdx.x;
  const int nbase = bin << 7;
  if (t < 128) c128[t] = 0;
  __syncthreads();
  const int s0 = bin * BINCAP;
  const int s1 = min(gcur[bin], s0 + BINCAP);
#pragma unroll 1
  for (int i = s0 + t; i < s1; i += 256) {
    const int p = binned[i];
    const int dlow = p >> 17;
    const int sv = p & 131071;
    const int slot = atomicAdd(&c128[dlow], 1);
    if (slot < CAP) {
      bucket[(nbase + dlow) * CAP + slot] = sv;
    } else {
      const int q = atomicAdd(&ovf[-2], 1);  // ovf[-2] == ovfCnt
      if (q < OVF_CAPN) { ovf[2 * q] = nbase + dlow; ovf[2 * q + 1] = sv; }
    }
  }
  __syncthreads();
  if (t < 128 && nbase + t < NN) {
    const int dc = min(c128[t], CAP);
    cnt[nbase + t] = c128[t];
    // pad to next multiple of 16 with dummy index NN (zero row) for branch-free agg
    const int pad = min((dc + 15) & ~15, CAP);
    int* __restrict__ brow = bucket + (nbase + t) * CAP;
#pragma unroll 1
    for (int q2 = dc; q2 < pad; ++q2) brow[q2] = NN;
  }
}

// cvt (h f32 -> hb bf16 rows) + zero row hb[NN] + x passthrough, one dispatch
__global__ __launch_bounds__(256) void cvtx_k(const float* __restrict__ h,
                                              unsigned* __restrict__ hb,
                                              const float* __restrict__ x,
                                              float* __restrict__ ox) {
  const int b = blockIdx.x;
  const int t = threadIdx.x;
  if (b < 3125) {
    const int i = b * 256 + t;             // 0..799999
    const float4* __restrict__ h4 = reinterpret_cast<const float4*>(h);
    const float4 a = h4[2 * i], c = h4[2 * i + 1];
    uint4 o;
    o.x = pk2(a.x, a.y); o.y = pk2(a.z, a.w);
    o.z = pk2(c.x, c.y); o.w = pk2(c.z, c.w);
    reinterpret_cast<uint4*>(hb)[i] = o;
  } else {
    if (b == 3125 && t < 32) hb[NN * 32 + t] = 0;   // zero row for dummy gathers
    const int i = (b - 3125) * 256 + t;
    if (i < (NN * 3) / 4)
      reinterpret_cast<float4*>(ox)[i] = reinterpret_cast<const float4*>(x)[i];
  }
}

// z[n] = hb[n] + sum_{j->n} hb[j].  Branch-free padded gather; FOUR nodes per wave
// (quad accumulators, 4 idx + 16 gathers in flight). lane = (slot s=l>>4, group g=l&15).
// Overflow edges (deg>CAP or bin overflow, ~never) patched in f32 before the bf16 pack.
__global__ __launch_bounds__(256) void agg_k(const unsigned short* __restrict__ hb,
                                             const int* __restrict__ cnt,
                                             const int* __restrict__ bucket,
                                             unsigned* __restrict__ zbu,
                                             const int* __restrict__ ovfCnt,
                                             const int* __restrict__ ovf) {
  const int l = threadIdx.x & 63;
  const int s = l >> 4, g = l & 15;
  int nb = blockIdx.x * 16 + (threadIdx.x >> 6) * 4;   // 6250*16 = 100000 exact
  nb = __builtin_amdgcn_readfirstlane(nb);
  const int n0 = nb, n1 = nb + 1, n2 = nb + 2, n3 = nb + 3;

  const int4 c4 = *reinterpret_cast<const int4*>(cnt + nb);  // nb%4==0 -> aligned
  const int nit0 = (min(c4.x, CAP) + 15) >> 4;
  const int nit1 = (min(c4.y, CAP) + 15) >> 4;
  const int nit2 = (min(c4.z, CAP) + 15) >> 4;
  const int nit3 = (min(c4.w, CAP) + 15) >> 4;
  const int nc = min(min(nit0, nit1), min(nit2, nit3));

  const int4* __restrict__ br0 = reinterpret_cast<const int4*>(bucket + n0 * CAP);
  const int4* __restrict__ br1 = reinterpret_cast<const int4*>(bucket + n1 * CAP);
  const int4* __restrict__ br2 = reinterpret_cast<const int4*>(bucket + n2 * CAP);
  const int4* __restrict__ br3 = reinterpret_cast<const int4*>(bucket + n3 * CAP);
  const uint2* __restrict__ h2 = reinterpret_cast<const uint2*>(hb);

  // self rows: only slot 0 seeds
  const uint2 s0v = h2[n0 * 16 + g];
  const uint2 s1v = h2[n1 * 16 + g];
  const uint2 s2v = h2[n2 * 16 + g];
  const uint2 s3v = h2[n3 * 16 + g];
  const unsigned z0 = (s == 0) ? s0v.x : 0u, z1 = (s == 0) ? s0v.y : 0u;
  const unsigned z2 = (s == 0) ? s1v.x : 0u, z3 = (s == 0) ? s1v.y : 0u;
  const unsigned z4 = (s == 0) ? s2v.x : 0u, z5 = (s == 0) ? s2v.y : 0u;
  const unsigned z6 = (s == 0) ? s3v.x : 0u, z7 = (s == 0) ? s3v.y : 0u;
  float a0 = __uint_as_float(z0 << 16), a1 = __uint_as_float(z0 & 0xffff0000u);
  float a2 = __uint_as_float(z1 << 16), a3 = __uint_as_float(z1 & 0xffff0000u);
  float b0 = __uint_as_float(z2 << 16), b1 = __uint_as_float(z2 & 0xffff0000u);
  float b2 = __uint_as_float(z3 << 16), b3 = __uint_as_float(z3 & 0xffff0000u);
  float c0 = __uint_as_float(z4 << 16), c1 = __uint_as_float(z4 & 0xffff0000u);
  float c2 = __uint_as_float(z5 << 16), c3 = __uint_as_float(z5 & 0xffff0000u);
  float d0 = __uint_as_float(z6 << 16), d1 = __uint_as_float(z6 & 0xffff0000u);
  float d2 = __uint_as_float(z7 << 16), d3 = __uint_as_float(z7 & 0xffff0000u);

#define ACCA(vv)                                   \
    a0 += __uint_as_float(vv.x << 16);             \
    a1 += __uint_as_float(vv.x & 0xffff0000u);     \
    a2 += __uint_as_float(vv.y << 16);             \
    a3 += __uint_as_float(vv.y & 0xffff0000u);
#define ACCB(vv)                                   \
    b0 += __uint_as_float(vv.x << 16);             \
    b1 += __uint_as_float(vv.x & 0xffff0000u);     \
    b2 += __uint_as_float(vv.y << 16);             \
    b3 += __uint_as_float(vv.y & 0xffff0000u);
#define ACCC(vv)                                   \
    c0 += __uint_as_float(vv.x << 16);             \
    c1 += __uint_as_float(vv.x & 0xffff0000u);     \
    c2 += __uint_as_float(vv.y << 16);             \
    c3 += __uint_as_float(vv.y & 0xffff0000u);
#define ACCD(vv)                                   \
    d0 += __uint_as_float(vv.x << 16);             \
    d1 += __uint_as_float(vv.x & 0xffff0000u);     \
    d2 += __uint_as_float(vv.y << 16);             \
    d3 += __uint_as_float(vv.y & 0xffff0000u);

#pragma unroll 1
  for (int it = 0; it < nc; ++it) {   // 4 idx + 16 gathers in flight
    const int4 q0 = br0[it * 4 + s];
    const int4 q1 = br1[it * 4 + s];
    const int4 q2 = br2[it * 4 + s];
    const int4 q3 = br3[it * 4 + s];
    const uint2 v0 = h2[q0.x * 16 + g];
    const uint2 v1 = h2[q0.y * 16 + g];
    const uint2 v2 = h2[q0.z * 16 + g];
    const uint2 v3 = h2[q0.w * 16 + g];
    const uint2 w0 = h2[q1.x * 16 + g];
    const uint2 w1 = h2[q1.y * 16 + g];
    const uint2 w2 = h2[q1.z * 16 + g];
    const uint2 w3 = h2[q1.w * 16 + g];
    const uint2 x0 = h2[q2.x * 16 + g];
    const uint2 x1 = h2[q2.y * 16 + g];
    const uint2 x2 = h2[q2.z * 16 + g];
    const uint2 x3 = h2[q2.w * 16 + g];
    const uint2 y0 = h2[q3.x * 16 + g];
    const uint2 y1 = h2[q3.y * 16 + g];
    const uint2 y2 = h2[q3.z * 16 + g];
    const uint2 y3 = h2[q3.w * 16 + g];
    ACCA(v0) ACCA(v1) ACCA(v2) ACCA(v3)
    ACCB(w0) ACCB(w1) ACCB(w2) ACCB(w3)
    ACCC(x0) ACCC(x1) ACCC(x2) ACCC(x3)
    ACCD(y0) ACCD(y1) ACCD(y2) ACCD(y3)
  }
#pragma unroll 1
  for (int it = nc; it < nit0; ++it) {   // wave-uniform tails
    const int4 q0 = br0[it * 4 + s];
    const uint2 v0 = h2[q0.x * 16 + g];
    const uint2 v1 = h2[q0.y * 16 + g];
    const uint2 v2 = h2[q0.z * 16 + g];
    const uint2 v3 = h2[q0.w * 16 + g];
    ACCA(v0) ACCA(v1) ACCA(v2) ACCA(v3)
  }
#pragma unroll 1
  for (int it = nc; it < nit1; ++it) {
    const int4 q1 = br1[it * 4 + s];
    const uint2 w0 = h2[q1.x * 16 + g];
    const uint2 w1 = h2[q1.y * 16 + g];
    const uint2 w2 = h2[q1.z * 16 + g];
    const uint2 w3 = h2[q1.w * 16 + g];
    ACCB(w0) ACCB(w1) ACCB(w2) ACCB(w3)
  }
#pragma unroll 1
  for (int it = nc; it < nit2; ++it) {
    const int4 q2 = br2[it * 4 + s];
    const uint2 x0 = h2[q2.x * 16 + g];
    const uint2 x1 = h2[q2.y * 16 + g];
    const uint2 x2 = h2[q2.z * 16 + g];
    const uint2 x3 = h2[q2.w * 16 + g];
    ACCC(x0) ACCC(x1) ACCC(x2) ACCC(x3)
  }
#pragma unroll 1
  for (int it = nc; it < nit3; ++it) {
    const int4 q3 = br3[it * 4 + s];
    const uint2 y0 = h2[q3.x * 16 + g];
    const uint2 y1 = h2[q3.y * 16 + g];
    const uint2 y2 = h2[q3.z * 16 + g];
    const uint2 y3 = h2[q3.w * 16 + g];
    ACCD(y0) ACCD(y1) ACCD(y2) ACCD(y3)
  }

  // reduce over slots (lane ^16, ^32)
  a0 += __shfl_xor(a0, 16); a1 += __shfl_xor(a1, 16);
  a2 += __shfl_xor(a2, 16); a3 += __shfl_xor(a3, 16);
  a0 += __shfl_xor(a0, 32); a1 += __shfl_xor(a1, 32);
  a2 += __shfl_xor(a2, 32); a3 += __shfl_xor(a3, 32);
  b0 += __shfl_xor(b0, 16); b1 += __shfl_xor(b1, 16);
  b2 += __shfl_xor(b2, 16); b3 += __shfl_xor(b3, 16);
  b0 += __shfl_xor(b0, 32); b1 += __shfl_xor(b1, 32);
  b2 += __shfl_xor(b2, 32); b3 += __shfl_xor(b3, 32);
  c0 += __shfl_xor(c0, 16); c1 += __shfl_xor(c1, 16);
  c2 += __shfl_xor(c2, 16); c3 += __shfl_xor(c3, 16);
  c0 += __shfl_xor(c0, 32); c1 += __shfl_xor(c1, 32);
  c2 += __shfl_xor(c2, 32); c3 += __shfl_xor(c3, 32);
  d0 += __shfl_xor(d0, 16); d1 += __shfl_xor(d1, 16);
  d2 += __shfl_xor(d2, 16); d3 += __shfl_xor(d3, 16);
  d0 += __shfl_xor(d0, 32); d1 += __shfl_xor(d1, 32);
  d2 += __shfl_xor(d2, 32); d3 += __shfl_xor(d3, 32);

  // overflow patch (ovfCnt ~always 0): f32 add into slot-0 totals before pack
  const int cv = min(ovfCnt[0], OVF_CAPN);
  if (cv > 0) {
#pragma unroll 1
    for (int p = 0; p < cv; ++p) {
      const int d = ovf[2 * p];
      if (d >= n0 && d <= n3) {
        const uint2 vv = h2[ovf[2 * p + 1] * 16 + g];
        const float e0 = __uint_as_float(vv.x << 16);
        const float e1 = __uint_as_float(vv.x & 0xffff0000u);
        const float e2 = __uint_as_float(vv.y << 16);
        const float e3 = __uint_as_float(vv.y & 0xffff0000u);
        if (d == n0)      { a0 += e0; a1 += e1; a2 += e2; a3 += e3; }
        else if (d == n1) { b0 += e0; b1 += e1; b2 += e2; b3 += e3; }
        else if (d == n2) { c0 += e0; c1 += e1; c2 += e2; c3 += e3; }
        else              { d0 += e0; d1 += e1; d2 += e2; d3 += e3; }
      }
    }
  }

  if (s == 0) {
    uint2 o;
    o.x = pk2(a0, a1); o.y = pk2(a2, a3);
    reinterpret_cast<uint2*>(zbu)[n0 * 32 + g] = o;   // zb rows: 256B, bf16 in first 128B
    o.x = pk2(b0, b1); o.y = pk2(b2, b3);
    reinterpret_cast<uint2*>(zbu)[n1 * 32 + g] = o;
    o.x = pk2(c0, c1); o.y = pk2(c2, c3);
    reinterpret_cast<uint2*>(zbu)[n2 * 32 + g] = o;
    o.x = pk2(d0, d1); o.y = pk2(d2, d3);
    reinterpret_cast<uint2*>(zbu)[n3 * 32 + g] = o;
  }
#undef ACCA
#undef ACCB
#undef ACCC
#undef ACCD
}

// MFMA MLP (verified round 7): per 128-node tile, D1^T = W1^T @ Z^T; relu; D2^T = W2^T @ C1^T.
template <int OUTBF>
__global__ __launch_bounds__(256) void mlp_mfma_k(
    const char* __restrict__ zb,        // bf16 z rows, stride 256B
    void* __restrict__ hout,
    const unsigned short* __restrict__ pw1, const float* __restrict__ b1,
    const unsigned short* __restrict__ pw2, const float* __restrict__ b2,
    const float* __restrict__ mask) {
  __shared__ unsigned ldsu[128 * 33];   // 16.9 KB
  const int tid = threadIdx.x;
  const int w = tid >> 6, l = tid & 63, g = l >> 4, mi = l & 15;
  const int m0 = blockIdx.x * 128;
  const int rbase = w * 32;

  // Z^T B-fragments: lane holds z[node(mi)][k = ks*32 + g*8 + j]
  s8v zf[2][2];
#pragma unroll
  for (int tm = 0; tm < 2; ++tm) {
    const int node = m0 + rbase + tm * 16 + mi;
    const int nc = node < NN ? node : NN - 1;
#pragma unroll
    for (int ks = 0; ks < 2; ++ks)
      zf[tm][ks] = *reinterpret_cast<const s8v*>(zb + nc * 256 + (ks * 32 + g * 8) * 2);
  }

  // GEMM1 (C-in = bias)
  f4v acc[4][2];
#pragma unroll
  for (int t = 0; t < 4; ++t) {
    const f4v bv = *reinterpret_cast<const f4v*>(b1 + t * 16 + g * 4);
    acc[t][0] = bv; acc[t][1] = bv;
  }
#pragma unroll
  for (int t = 0; t < 4; ++t) {
#pragma unroll
    for (int ks = 0; ks < 2; ++ks) {
      const s8v wf = *reinterpret_cast<const s8v*>(pw1 + ((t * 2 + ks) * 64 + l) * 8);
#pragma unroll
      for (int tm = 0; tm < 2; ++tm)
        acc[t][tm] = __builtin_amdgcn_mfma_f32_16x16x32_bf16(wf, zf[tm][ks], acc[t][tm], 0, 0, 0);
    }
  }

  // relu + pack -> LDS (unsigned scalar stores; row stride 33 words)
#pragma unroll
  for (int t = 0; t < 4; ++t) {
#pragma unroll
    for (int tm = 0; tm < 2; ++tm) {
      const f4v a = acc[t][tm];
      const int row = rbase + tm * 16 + mi;
      const int base = row * 33 + t * 8 + g * 2;
      ldsu[base]     = pk2(fmaxf(a.x, 0.f), fmaxf(a.y, 0.f));
      ldsu[base + 1] = pk2(fmaxf(a.z, 0.f), fmaxf(a.w, 0.f));
    }
  }
  __syncthreads();

  // GEMM2 B-fragments from LDS
  s8v cf[2][2];
#pragma unroll
  for (int tm = 0; tm < 2; ++tm) {
    const int row = rbase + tm * 16 + mi;
#pragma unroll
    for (int ks = 0; ks < 2; ++ks) {
      const int b0 = row * 33 + ks * 16 + g * 4;
      U8 u8;
      u8.u[0] = ldsu[b0 + 0];
      u8.u[1] = ldsu[b0 + 1];
      u8.u[2] = ldsu[b0 + 2];
      u8.u[3] = ldsu[b0 + 3];
      cf[tm][ks] = u8.s;
    }
  }

  f4v acc2[4][2];
#pragma unroll
  for (int t = 0; t < 4; ++t) {
    const f4v bv = *reinterpret_cast<const f4v*>(b2 + t * 16 + g * 4);
    acc2[t][0] = bv; acc2[t][1] = bv;
  }
#pragma unroll
  for (int t = 0; t < 4; ++t) {
#pragma unroll
    for (int ks = 0; ks < 2; ++ks) {
      const s8v wf = *reinterpret_cast<const s8v*>(pw2 + ((t * 2 + ks) * 64 + l) * 8);
#pragma unroll
      for (int tm = 0; tm < 2; ++tm)
        acc2[t][tm] = __builtin_amdgcn_mfma_f32_16x16x32_bf16(wf, cf[tm][ks], acc2[t][tm], 0, 0, 0);
    }
  }

  // epilogue: direct fragment stores
  if (OUTBF) {
    unsigned* __restrict__ ho = reinterpret_cast<unsigned*>(hout);
#pragma unroll
    for (int tm = 0; tm < 2; ++tm) {
      const int node = m0 + rbase + tm * 16 + mi;
      if (node < NN) {
#pragma unroll
        for (int t = 0; t < 4; ++t) {
          const f4v a = acc2[t][tm];
          const int idx = node * 32 + t * 8 + g * 2;
          uint2 p;
          p.x = pk2(a.x, a.y);
          p.y = pk2(a.z, a.w);
          *reinterpret_cast<uint2*>(&ho[idx]) = p;
        }
      }
    }
  } else {
    float* __restrict__ fo = reinterpret_cast<float*>(hout);
#pragma unroll
    for (int tm = 0; tm < 2; ++tm) {
      const int node = m0 + rbase + tm * 16 + mi;
      if (node < NN) {
        const float mv = mask[node];
#pragma unroll
        for (int t = 0; t < 4; ++t) {
          f4v v = acc2[t][tm];
          v *= mv;
          *reinterpret_cast<f4v*>(fo + node * 64 + t * 16 + g * 4) = v;
        }
      }
    }
  }
}

extern "C" void kernel_launch(void* const* d_in, const int* in_sizes, int n_in,
                              void* d_out, int out_size, void* d_ws, size_t ws_size,
                              hipStream_t stream) {
  (void)in_sizes; (void)n_in; (void)out_size; (void)ws_size;
  const float* h    = (const float*)d_in[0];
  const float* x    = (const float*)d_in[1];
  const int*   ei   = (const int*)d_in[2];
  const float* mask = (const float*)d_in[3];
  const float* W1_0 = (const float*)d_in[4];
  const float* b1_0 = (const float*)d_in[5];
  const float* W2_0 = (const float*)d_in[6];
  const float* b2_0 = (const float*)d_in[7];
  const float* W1_1 = (const float*)d_in[8];
  const float* b1_1 = (const float*)d_in[9];
  const float* W2_1 = (const float*)d_in[10];
  const float* b2_1 = (const float*)d_in[11];
  float* out = (float*)d_out;

  const int* src = ei;       // edge_index[0]
  const int* dst = ei + EE;  // edge_index[1]

  int* wsp       = (int*)d_ws;
  int* gcur      = wsp;
  int* ovfCnt    = wsp + OVFC_OFF;
  int* ovf       = wsp + OVF_OFF;
  int* cnt       = wsp + CNT_OFF;
  int* bucket    = wsp + BUCK_OFF;
  int* binned    = wsp + BINNED_OFF;
  unsigned* hb   = (unsigned*)(wsp + HB_OFF);      // bf16 h (+zero row), later bf16 h1
  unsigned short* pw = (unsigned short*)(wsp + PW_OFF);
  const unsigned short* hbs = (const unsigned short*)hb;
  unsigned* zbu  = (unsigned*)d_out;  // bf16 z rows at node*256B
  char* zb       = (char*)d_out;

  // --- edge structure build (once, reused by both layers) ---
  setup_k<<<1, 256, 0, stream>>>(W1_0, W2_0, W1_1, W2_1, pw, wsp);  // gcur init + pack
  scatter_k<<<256, 256, 0, stream>>>(src, dst, gcur, binned, ovf);
  bucketize_k<<<782, 256, 0, stream>>>(gcur, binned, bucket, cnt, ovf);

  // --- h -> bf16 (+ zero row) + x passthrough (binned dead; region becomes hb) ---
  cvtx_k<<<3418, 256, 0, stream>>>(h, hb, x, out + NN * 64);

  // --- layer 1 ---
  agg_k<<<6250, 256, 0, stream>>>(hbs, cnt, bucket, zbu, ovfCnt, ovf);
  mlp_mfma_k<1><<<782, 256, 0, stream>>>(zb, hb, pw, b1_0, pw + 4096, b2_0, nullptr);

  // --- layer 2 ---
  agg_k<<<6250, 256, 0, stream>>>(hbs, cnt, bucket, zbu, ovfCnt, ovf);
  mlp_mfma_k<0><<<782, 256, 0, stream>>>(zb, out, pw + 8192, b1_1, pw + 12288, b2_1, mask);
}

// Round 13
// 142.798 us; speedup vs baseline: 1.0525x; 1.0525x over previous
//
#include <hip/hip_runtime.h>

// GIN block, 2 layers: h = mlp(h + segsum(h[src], dst)); out = (h*mask, x)
// N=100000, E=1600000, D=64.
// Round-13 = consolidation of best-measured components:
//  - agg: round-11's TWO-node-per-wave gather (50k waves -> occupancy ~68%; round-12's
//    4-node halved wave count, occupancy 36%, and was net slower)
//  - ovf patch folded into agg (round-12's verified win): 8 dispatches, no CAS kernel
//  - setup/scatter/bucketize/cvtx/mlp_mfma unchanged (verified rounds 7-12).

#define NN 100000
#define EE 1600000
#define CAP 48
#define NBIN 1024
#define BINCAP 2688
#define CHB 6250
#define OVF_CAPN 8000

// ws layout (ints):
//   gcur     @ 0        (1024)   -- init b*BINCAP by setup_k
//   ovfCnt   @ 1024     (1)      -- zeroed by setup_k
//   ovf      @ 1026     (2*8000)
//   cnt      @ 19200    (100000)
//   bucket   @ 119296   (NN*CAP)
//   binned   @ 4919296  (NBIN*BINCAP = 2752512) } binned dead after bucketize ->
//   hb/hb1   @ 4919296  (3200032)               } bf16 h / h1 + zero row at hb[NN]
//   pw       @ 8119328  (16384 shorts)
#define OVFC_OFF   1024
#define OVF_OFF    1026
#define CNT_OFF    19200
#define BUCK_OFF   119296
#define BINNED_OFF 4919296
#define HB_OFF     4919296
#define PW_OFF     8119328

typedef __attribute__((ext_vector_type(8))) short s8v;
typedef __attribute__((ext_vector_type(4))) float f4v;

union U8 { unsigned u[4]; s8v s; };

static __device__ __forceinline__ unsigned short f2bf(float f) {
  unsigned u = __float_as_uint(f);
  return (unsigned short)((u + 0x7FFF + ((u >> 16) & 1)) >> 16);  // RTNE
}
static __device__ __forceinline__ float bf2f(unsigned short s) {
  return __uint_as_float(((unsigned)s) << 16);
}
static __device__ __forceinline__ unsigned pk2(float lo, float hi) {
  return (unsigned)f2bf(lo) | ((unsigned)f2bf(hi) << 16);
}

// setup: gcur[b] = b*BINCAP, ovfCnt = 0, pack W[64][64] f32 row-major -> A-frag bf16:
// pw[m*4096 + ((t*2+ks)*64 + l)*8 + j] = bf16(W[ks*32 + (l>>4)*8 + j][t*16 + (l&15)])
__global__ __launch_bounds__(256) void setup_k(const float* __restrict__ W1a,
                                               const float* __restrict__ W2a,
                                               const float* __restrict__ W1b,
                                               const float* __restrict__ W2b,
                                               unsigned short* __restrict__ pw,
                                               int* __restrict__ wsp) {
  const int t = threadIdx.x;
#pragma unroll
  for (int i = t; i < NBIN; i += 256) wsp[i] = i * BINCAP;  // gcur
  if (t == 0) wsp[OVFC_OFF] = 0;
  const float* Ws[4] = {W1a, W2a, W1b, W2b};
#pragma unroll
  for (int m = 0; m < 4; ++m) {
    const float* __restrict__ W = Ws[m];
#pragma unroll 1
    for (int i = 0; i < 16; ++i) {
      const int e = i * 256 + t;           // 0..4095
      const int j = e & 7;
      const int lv = (e >> 3) & 63;
      const int ks = (e >> 9) & 1;
      const int tt = e >> 10;
      const int k = ks * 32 + (lv >> 4) * 8 + j;
      const int n = tt * 16 + (lv & 15);
      pw[m * 4096 + e] = f2bf(W[k * 64 + n]);
    }
  }
}

// single-pass binning: LDS block-hist -> one global cursor bump per (block,bin) -> scatter
__global__ __launch_bounds__(256) void scatter_k(const int* __restrict__ src,
                                                 const int* __restrict__ dst,
                                                 int* __restrict__ gcur,
                                                 int* __restrict__ binned,
                                                 int* __restrict__ ovf) {
  __shared__ int hist[NBIN], base[NBIN], lcnt[NBIN];
  const int t = threadIdx.x;
#pragma unroll
  for (int b = t; b < NBIN; b += 256) { hist[b] = 0; lcnt[b] = 0; }
  __syncthreads();
  const int s = blockIdx.x * CHB;
#pragma unroll 1
  for (int p = t; p < CHB / 2; p += 256) {
    const int2 dd = *reinterpret_cast<const int2*>(dst + s + 2 * p);
    atomicAdd(&hist[dd.x >> 7], 1);
    atomicAdd(&hist[dd.y >> 7], 1);
  }
  __syncthreads();
#pragma unroll
  for (int b = t; b < NBIN; b += 256) {
    const int c = hist[b];
    base[b] = c ? atomicAdd(&gcur[b], c) : 0;
  }
  __syncthreads();
#pragma unroll 1
  for (int p = t; p < CHB / 2; p += 256) {
    const int i = s + 2 * p;
    const int2 dd = *reinterpret_cast<const int2*>(dst + i);
    const int2 ss = *reinterpret_cast<const int2*>(src + i);
    {
      const int bin = dd.x >> 7;
      const int slot = base[bin] + atomicAdd(&lcnt[bin], 1);
      if (slot < (bin + 1) * BINCAP) {
        binned[slot] = ((dd.x & 127) << 17) | ss.x;
      } else {
        const int q = atomicAdd(&ovf[-2], 1);
        if (q < OVF_CAPN) { ovf[2 * q] = dd.x; ovf[2 * q + 1] = ss.x; }
      }
    }
    {
      const int bin = dd.y >> 7;
      const int slot = base[bin] + atomicAdd(&lcnt[bin], 1);
      if (slot < (bin + 1) * BINCAP) {
        binned[slot] = ((dd.y & 127) << 17) | ss.y;
      } else {
        const int q = atomicAdd(&ovf[-2], 1);
        if (q < OVF_CAPN) { ovf[2 * q] = dd.y; ovf[2 * q + 1] = ss.y; }
      }
    }
  }
}

__global__ __launch_bounds__(256) void bucketize_k(const int* __restrict__ gcur,
                                                   const int* __restrict__ binned,
                                                   int* __restrict__ bucket,
                                                   int* __restrict__ cnt,
                                                   int* __restrict__ ovf) {
  __shared__ int c128[128];
  const int t = threadIdx.x;
  const int bin = blockIdx.x;
  const int nbase = bin << 7;
  if (t < 128) c128[t] = 0;
  __syncthreads();
  const int s0 = bin * BINCAP;
  const int s1 = min(gcur[bin], s0 + BINCAP);
#pragma unroll 1
  for (int i = s0 + t; i < s1; i += 256) {
    const int p = binned[i];
    const int dlow = p >> 17;
    const int sv = p & 131071;
    const int slot = atomicAdd(&c128[dlow], 1);
    if (slot < CAP) {
      bucket[(nbase + dlow) * CAP + slot] = sv;
    } else {
      const int q = atomicAdd(&ovf[-2], 1);  // ovf[-2] == ovfCnt
      if (q < OVF_CAPN) { ovf[2 * q] = nbase + dlow; ovf[2 * q + 1] = sv; }
    }
  }
  __syncthreads();
  if (t < 128 && nbase + t < NN) {
    const int dc = min(c128[t], CAP);
    cnt[nbase + t] = c128[t];
    // pad to next multiple of 16 with dummy index NN (zero row) for branch-free agg
    const int pad = min((dc + 15) & ~15, CAP);
    int* __restrict__ brow = bucket + (nbase + t) * CAP;
#pragma unroll 1
    for (int q2 = dc; q2 < pad; ++q2) brow[q2] = NN;
  }
}

// cvt (h f32 -> hb bf16 rows) + zero row hb[NN] + x passthrough, one dispatch
__global__ __launch_bounds__(256) void cvtx_k(const float* __restrict__ h,
                                              unsigned* __restrict__ hb,
                                              const float* __restrict__ x,
                                              float* __restrict__ ox) {
  const int b = blockIdx.x;
  const int t = threadIdx.x;
  if (b < 3125) {
    const int i = b * 256 + t;             // 0..799999
    const float4* __restrict__ h4 = reinterpret_cast<const float4*>(h);
    const float4 a = h4[2 * i], c = h4[2 * i + 1];
    uint4 o;
    o.x = pk2(a.x, a.y); o.y = pk2(a.z, a.w);
    o.z = pk2(c.x, c.y); o.w = pk2(c.z, c.w);
    reinterpret_cast<uint4*>(hb)[i] = o;
  } else {
    if (b == 3125 && t < 32) hb[NN * 32 + t] = 0;   // zero row for dummy gathers
    const int i = (b - 3125) * 256 + t;
    if (i < (NN * 3) / 4)
      reinterpret_cast<float4*>(ox)[i] = reinterpret_cast<const float4*>(x)[i];
  }
}

// z[n] = hb[n] + sum_{j->n} hb[j].  Branch-free padded gather; TWO nodes per wave
// (round-11's measured-best TLP/ILP point). lane = (slot s=l>>4, group g=l&15).
// Overflow edges (deg>CAP or bin overflow, ~never) patched in f32 after the slot
// reduce (counted once: only s==0 lanes pack).
__global__ __launch_bounds__(256) void agg_k(const unsigned short* __restrict__ hb,
                                             const int* __restrict__ cnt,
                                             const int* __restrict__ bucket,
                                             unsigned* __restrict__ zbu,
                                             const int* __restrict__ ovfCnt,
                                             const int* __restrict__ ovf) {
  const int l = threadIdx.x & 63;
  const int s = l >> 4, g = l & 15;
  int nb = blockIdx.x * 8 + (threadIdx.x >> 6) * 2;   // 12500*8 = 100000 exact
  nb = __builtin_amdgcn_readfirstlane(nb);
  const int n0 = nb, n1 = nb + 1;

  const int2 c2 = *reinterpret_cast<const int2*>(cnt + n0);  // n0 even -> aligned
  const int deg0 = min(c2.x, CAP), deg1 = min(c2.y, CAP);
  const int nit0 = (deg0 + 15) >> 4, nit1 = (deg1 + 15) >> 4;
  const int nc = min(nit0, nit1);

  const int4* __restrict__ br0 = reinterpret_cast<const int4*>(bucket + n0 * CAP);
  const int4* __restrict__ br1 = reinterpret_cast<const int4*>(bucket + n1 * CAP);
  const uint2* __restrict__ h2 = reinterpret_cast<const uint2*>(hb);

  // self rows: only slot 0 seeds
  const uint2 sv0 = h2[n0 * 16 + g];
  const uint2 sv1 = h2[n1 * 16 + g];
  const unsigned p00 = (s == 0) ? sv0.x : 0u, p01 = (s == 0) ? sv0.y : 0u;
  const unsigned p10 = (s == 0) ? sv1.x : 0u, p11 = (s == 0) ? sv1.y : 0u;
  float a0 = __uint_as_float(p00 << 16), a1 = __uint_as_float(p00 & 0xffff0000u);
  float a2 = __uint_as_float(p01 << 16), a3 = __uint_as_float(p01 & 0xffff0000u);
  float b0 = __uint_as_float(p10 << 16), b1 = __uint_as_float(p10 & 0xffff0000u);
  float b2 = __uint_as_float(p11 << 16), b3 = __uint_as_float(p11 & 0xffff0000u);

#define ACCA(vv)                                   \
    a0 += __uint_as_float(vv.x << 16);             \
    a1 += __uint_as_float(vv.x & 0xffff0000u);     \
    a2 += __uint_as_float(vv.y << 16);             \
    a3 += __uint_as_float(vv.y & 0xffff0000u);
#define ACCB(vv)                                   \
    b0 += __uint_as_float(vv.x << 16);             \
    b1 += __uint_as_float(vv.x & 0xffff0000u);     \
    b2 += __uint_as_float(vv.y << 16);             \
    b3 += __uint_as_float(vv.y & 0xffff0000u);

#pragma unroll 1
  for (int it = 0; it < nc; ++it) {                 // interleaved: 2 idx + 8 gathers in flight
    const int4 q0 = br0[it * 4 + s];
    const int4 q1 = br1[it * 4 + s];
    const uint2 v0 = h2[q0.x * 16 + g];
    const uint2 v1 = h2[q0.y * 16 + g];
    const uint2 v2 = h2[q0.z * 16 + g];
    const uint2 v3 = h2[q0.w * 16 + g];
    const uint2 w0 = h2[q1.x * 16 + g];
    const uint2 w1 = h2[q1.y * 16 + g];
    const uint2 w2 = h2[q1.z * 16 + g];
    const uint2 w3 = h2[q1.w * 16 + g];
    ACCA(v0) ACCA(v1) ACCA(v2) ACCA(v3)
    ACCB(w0) ACCB(w1) ACCB(w2) ACCB(w3)
  }
#pragma unroll 1
  for (int it = nc; it < nit0; ++it) {              // wave-uniform tail, node 0
    const int4 q0 = br0[it * 4 + s];
    const uint2 v0 = h2[q0.x * 16 + g];
    const uint2 v1 = h2[q0.y * 16 + g];
    const uint2 v2 = h2[q0.z * 16 + g];
    const uint2 v3 = h2[q0.w * 16 + g];
    ACCA(v0) ACCA(v1) ACCA(v2) ACCA(v3)
  }
#pragma unroll 1
  for (int it = nc; it < nit1; ++it) {              // wave-uniform tail, node 1
    const int4 q1 = br1[it * 4 + s];
    const uint2 w0 = h2[q1.x * 16 + g];
    const uint2 w1 = h2[q1.y * 16 + g];
    const uint2 w2 = h2[q1.z * 16 + g];
    const uint2 w3 = h2[q1.w * 16 + g];
    ACCB(w0) ACCB(w1) ACCB(w2) ACCB(w3)
  }
#undef ACCA
#undef ACCB

  // reduce over slots (lane ^16, ^32)
  a0 += __shfl_xor(a0, 16); a1 += __shfl_xor(a1, 16);
  a2 += __shfl_xor(a2, 16); a3 += __shfl_xor(a3, 16);
  a0 += __shfl_xor(a0, 32); a1 += __shfl_xor(a1, 32);
  a2 += __shfl_xor(a2, 32); a3 += __shfl_xor(a3, 32);
  b0 += __shfl_xor(b0, 16); b1 += __shfl_xor(b1, 16);
  b2 += __shfl_xor(b2, 16); b3 += __shfl_xor(b3, 16);
  b0 += __shfl_xor(b0, 32); b1 += __shfl_xor(b1, 32);
  b2 += __shfl_xor(b2, 32); b3 += __shfl_xor(b3, 32);

  // overflow patch (ovfCnt ~always 0): f32 add after reduce, before pack -> counted once
  const int cv = min(ovfCnt[0], OVF_CAPN);
  if (cv > 0) {
#pragma unroll 1
    for (int p = 0; p < cv; ++p) {
      const int d = ovf[2 * p];
      if (d == n0 || d == n1) {
        const uint2 vv = h2[ovf[2 * p + 1] * 16 + g];
        const float e0 = __uint_as_float(vv.x << 16);
        const float e1 = __uint_as_float(vv.x & 0xffff0000u);
        const float e2 = __uint_as_float(vv.y << 16);
        const float e3 = __uint_as_float(vv.y & 0xffff0000u);
        if (d == n0) { a0 += e0; a1 += e1; a2 += e2; a3 += e3; }
        else         { b0 += e0; b1 += e1; b2 += e2; b3 += e3; }
      }
    }
  }

  if (s == 0) {
    uint2 o0, o1;
    o0.x = pk2(a0, a1); o0.y = pk2(a2, a3);
    o1.x = pk2(b0, b1); o1.y = pk2(b2, b3);
    reinterpret_cast<uint2*>(zbu)[n0 * 32 + g] = o0;  // zb row: 256B, bf16 in first 128B
    reinterpret_cast<uint2*>(zbu)[n1 * 32 + g] = o1;
  }
}

// MFMA MLP (verified round 7): per 128-node tile, D1^T = W1^T @ Z^T; relu; D2^T = W2^T @ C1^T.
template <int OUTBF>
__global__ __launch_bounds__(256) void mlp_mfma_k(
    const char* __restrict__ zb,        // bf16 z rows, stride 256B
    void* __restrict__ hout,
    const unsigned short* __restrict__ pw1, const float* __restrict__ b1,
    const unsigned short* __restrict__ pw2, const float* __restrict__ b2,
    const float* __restrict__ mask) {
  __shared__ unsigned ldsu[128 * 33];   // 16.9 KB
  const int tid = threadIdx.x;
  const int w = tid >> 6, l = tid & 63, g = l >> 4, mi = l & 15;
  const int m0 = blockIdx.x * 128;
  const int rbase = w * 32;

  // Z^T B-fragments: lane holds z[node(mi)][k = ks*32 + g*8 + j]
  s8v zf[2][2];
#pragma unroll
  for (int tm = 0; tm < 2; ++tm) {
    const int node = m0 + rbase + tm * 16 + mi;
    const int nc = node < NN ? node : NN - 1;
#pragma unroll
    for (int ks = 0; ks < 2; ++ks)
      zf[tm][ks] = *reinterpret_cast<const s8v*>(zb + nc * 256 + (ks * 32 + g * 8) * 2);
  }

  // GEMM1 (C-in = bias)
  f4v acc[4][2];
#pragma unroll
  for (int t = 0; t < 4; ++t) {
    const f4v bv = *reinterpret_cast<const f4v*>(b1 + t * 16 + g * 4);
    acc[t][0] = bv; acc[t][1] = bv;
  }
#pragma unroll
  for (int t = 0; t < 4; ++t) {
#pragma unroll
    for (int ks = 0; ks < 2; ++ks) {
      const s8v wf = *reinterpret_cast<const s8v*>(pw1 + ((t * 2 + ks) * 64 + l) * 8);
#pragma unroll
      for (int tm = 0; tm < 2; ++tm)
        acc[t][tm] = __builtin_amdgcn_mfma_f32_16x16x32_bf16(wf, zf[tm][ks], acc[t][tm], 0, 0, 0);
    }
  }

  // relu + pack -> LDS (unsigned scalar stores; row stride 33 words)
#pragma unroll
  for (int t = 0; t < 4; ++t) {
#pragma unroll
    for (int tm = 0; tm < 2; ++tm) {
      const f4v a = acc[t][tm];
      const int row = rbase + tm * 16 + mi;
      const int base = row * 33 + t * 8 + g * 2;
      ldsu[base]     = pk2(fmaxf(a.x, 0.f), fmaxf(a.y, 0.f));
      ldsu[base + 1] = pk2(fmaxf(a.z, 0.f), fmaxf(a.w, 0.f));
    }
  }
  __syncthreads();

  // GEMM2 B-fragments from LDS
  s8v cf[2][2];
#pragma unroll
  for (int tm = 0; tm < 2; ++tm) {
    const int row = rbase + tm * 16 + mi;
#pragma unroll
    for (int ks = 0; ks < 2; ++ks) {
      const int b0 = row * 33 + ks * 16 + g * 4;
      U8 u8;
      u8.u[0] = ldsu[b0 + 0];
      u8.u[1] = ldsu[b0 + 1];
      u8.u[2] = ldsu[b0 + 2];
      u8.u[3] = ldsu[b0 + 3];
      cf[tm][ks] = u8.s;
    }
  }

  f4v acc2[4][2];
#pragma unroll
  for (int t = 0; t < 4; ++t) {
    const f4v bv = *reinterpret_cast<const f4v*>(b2 + t * 16 + g * 4);
    acc2[t][0] = bv; acc2[t][1] = bv;
  }
#pragma unroll
  for (int t = 0; t < 4; ++t) {
#pragma unroll
    for (int ks = 0; ks < 2; ++ks) {
      const s8v wf = *reinterpret_cast<const s8v*>(pw2 + ((t * 2 + ks) * 64 + l) * 8);
#pragma unroll
      for (int tm = 0; tm < 2; ++tm)
        acc2[t][tm] = __builtin_amdgcn_mfma_f32_16x16x32_bf16(wf, cf[tm][ks], acc2[t][tm], 0, 0, 0);
    }
  }

  // epilogue: direct fragment stores
  if (OUTBF) {
    unsigned* __restrict__ ho = reinterpret_cast<unsigned*>(hout);
#pragma unroll
    for (int tm = 0; tm < 2; ++tm) {
      const int node = m0 + rbase + tm * 16 + mi;
      if (node < NN) {
#pragma unroll
        for (int t = 0; t < 4; ++t) {
          const f4v a = acc2[t][tm];
          const int idx = node * 32 + t * 8 + g * 2;
          uint2 p;
          p.x = pk2(a.x, a.y);
          p.y = pk2(a.z, a.w);
          *reinterpret_cast<uint2*>(&ho[idx]) = p;
        }
      }
    }
  } else {
    float* __restrict__ fo = reinterpret_cast<float*>(hout);
#pragma unroll
    for (int tm = 0; tm < 2; ++tm) {
      const int node = m0 + rbase + tm * 16 + mi;
      if (node < NN) {
        const float mv = mask[node];
#pragma unroll
        for (int t = 0; t < 4; ++t) {
          f4v v = acc2[t][tm];
          v *= mv;
          *reinterpret_cast<f4v*>(fo + node * 64 + t * 16 + g * 4) = v;
        }
      }
    }
  }
}

extern "C" void kernel_launch(void* const* d_in, const int* in_sizes, int n_in,
                              void* d_out, int out_size, void* d_ws, size_t ws_size,
                              hipStream_t stream) {
  (void)in_sizes; (void)n_in; (void)out_size; (void)ws_size;
  const float* h    = (const float*)d_in[0];
  const float* x    = (const float*)d_in[1];
  const int*   ei   = (const int*)d_in[2];
  const float* mask = (const float*)d_in[3];
  const float* W1_0 = (const float*)d_in[4];
  const float* b1_0 = (const float*)d_in[5];
  const float* W2_0 = (const float*)d_in[6];
  const float* b2_0 = (const float*)d_in[7];
  const float* W1_1 = (const float*)d_in[8];
  const float* b1_1 = (const float*)d_in[9];
  const float* W2_1 = (const float*)d_in[10];
  const float* b2_1 = (const float*)d_in[11];
  float* out = (float*)d_out;

  const int* src = ei;       // edge_index[0]
  const int* dst = ei + EE;  // edge_index[1]

  int* wsp       = (int*)d_ws;
  int* gcur      = wsp;
  int* ovfCnt    = wsp + OVFC_OFF;
  int* ovf       = wsp + OVF_OFF;
  int* cnt       = wsp + CNT_OFF;
  int* bucket    = wsp + BUCK_OFF;
  int* binned    = wsp + BINNED_OFF;
  unsigned* hb   = (unsigned*)(wsp + HB_OFF);      // bf16 h (+zero row), later bf16 h1
  unsigned short* pw = (unsigned short*)(wsp + PW_OFF);
  const unsigned short* hbs = (const unsigned short*)hb;
  unsigned* zbu  = (unsigned*)d_out;  // bf16 z rows at node*256B
  char* zb       = (char*)d_out;

  // --- edge structure build (once, reused by both layers) ---
  setup_k<<<1, 256, 0, stream>>>(W1_0, W2_0, W1_1, W2_1, pw, wsp);  // gcur init + pack
  scatter_k<<<256, 256, 0, stream>>>(src, dst, gcur, binned, ovf);
  bucketize_k<<<782, 256, 0, stream>>>(gcur, binned, bucket, cnt, ovf);

  // --- h -> bf16 (+ zero row) + x passthrough (binned dead; region becomes hb) ---
  cvtx_k<<<3418, 256, 0, stream>>>(h, hb, x, out + NN * 64);

  // --- layer 1 ---
  agg_k<<<12500, 256, 0, stream>>>(hbs, cnt, bucket, zbu, ovfCnt, ovf);
  mlp_mfma_k<1><<<782, 256, 0, stream>>>(zb, hb, pw, b1_0, pw + 4096, b2_0, nullptr);

  // --- layer 2 ---
  agg_k<<<12500, 256, 0, stream>>>(hbs, cnt, bucket, zbu, ovfCnt, ovf);
  mlp_mfma_k<0><<<782, 256, 0, stream>>>(zb, out, pw + 8192, b1_1, pw + 12288, b2_1, mask);
}